// Round 1
// baseline (415.320 us; speedup 1.0000x reference)
//
#include <hip/hip_runtime.h>

// GCN edge-predictor encoder:
//   deg/dinv -> CSR build -> aggA = A_norm @ x -> h = aggA@W_base + b
//   -> aggH = A_norm @ h -> m = relu(aggH@W_mu+b_mu), s = relu(aggH@W_ls+b_ls)
// Aggregation commutes with the linear layer, so layers 2a/2b share one
// aggregation pass (2 passes total instead of 3).

#define CH 128

__global__ void count_kernel(const int* __restrict__ ei, int E, int* __restrict__ cnt) {
  int e = blockIdx.x * blockDim.x + threadIdx.x;
  if (e < E) atomicAdd(&cnt[ei[E + e]], 1);
}

// Single-block scan: rowptr = exclusive_scan(cnt), cursor = rowptr copy,
// dinv = rsqrt(cnt + 1)  (the +1 is the self-loop).
__global__ __launch_bounds__(1024) void scan_kernel(const int* __restrict__ cnt,
    int* __restrict__ rowptr, int* __restrict__ cursor, float* __restrict__ dinv, int n) {
  __shared__ int sdata[1024];
  int tid = threadIdx.x;
  int running = 0;
  for (int base = 0; base < n; base += 1024) {
    int i = base + tid;
    int v = (i < n) ? cnt[i] : 0;
    sdata[tid] = v;
    __syncthreads();
    for (int off = 1; off < 1024; off <<= 1) {
      int t = (tid >= off) ? sdata[tid - off] : 0;
      __syncthreads();
      sdata[tid] += t;
      __syncthreads();
    }
    int incl = sdata[tid];
    int excl = incl - v;
    if (i < n) {
      rowptr[i] = running + excl;
      cursor[i] = running + excl;
      dinv[i]   = rsqrtf((float)(v + 1));
    }
    running += sdata[1023];
    __syncthreads();
  }
  if (tid == 0) rowptr[n] = running;
}

__global__ void fill_kernel(const int* __restrict__ ei, int E,
                            int* __restrict__ cursor, int* __restrict__ col) {
  int e = blockIdx.x * blockDim.x + threadIdx.x;
  if (e < E) {
    int d = ei[E + e];
    int pos = atomicAdd(&cursor[d], 1);
    col[pos] = ei[e];
  }
}

// One wave (64 lanes) per node; lane owns 2 channels (float2).
// out[i] = dinv[i]^2 * feat[i] + sum_{e:dst=i} dinv[i]*dinv[src] * feat[src]
__global__ __launch_bounds__(256) void agg_kernel(const float* __restrict__ feat,
    const int* __restrict__ rowptr, const int* __restrict__ col,
    const float* __restrict__ dinv, float* __restrict__ out, int n) {
  int w = (blockIdx.x * 256 + threadIdx.x) >> 6;
  if (w >= n) return;
  int lane = threadIdx.x & 63;
  float di = dinv[w];
  const float2* f2 = (const float2*)feat;
  float2 x = f2[(size_t)w * 64 + lane];
  float2 acc;
  acc.x = x.x * di * di;
  acc.y = x.y * di * di;
  int s = rowptr[w], e = rowptr[w + 1];
  for (int j = s; j < e; ++j) {
    int src = col[j];
    float wt = di * dinv[src];
    float2 v = f2[(size_t)src * 64 + lane];
    acc.x = fmaf(wt, v.x, acc.x);
    acc.y = fmaf(wt, v.y, acc.y);
  }
  ((float2*)out)[(size_t)w * 64 + lane] = acc;
}

// f32 VALU GEMM: out[M,128] = A[M,128] @ W[128,128] + bias (+ optional relu).
// 64-row tile per block, 8x4 register micro-tile per thread, A staged
// transposed in LDS, W staged in 32-k chunks (48KB LDS total -> 3 blocks/CU).
__global__ __launch_bounds__(256) void gemm_kernel(
    const float* __restrict__ A, const float* __restrict__ W,
    const float* __restrict__ bias, float* __restrict__ out, int M, int relu) {
  __shared__ float As[128][64];   // [k][m] 32KB
  __shared__ float Ws[32][128];   // [k][n] 16KB
  const int tid = threadIdx.x;
  const int m0 = blockIdx.x * 64;

  const float4* A4 = (const float4*)A;
  #pragma unroll
  for (int i = 0; i < 8; ++i) {
    int j = tid + i * 256;        // float4 index within 64x128 tile
    int r = j >> 5;               // row 0..63
    int c = j & 31;               // f4-col 0..31
    int row = m0 + r;
    float4 v = make_float4(0.f, 0.f, 0.f, 0.f);
    if (row < M) v = A4[(size_t)row * 32 + c];
    int kk = c << 2;
    As[kk + 0][r] = v.x; As[kk + 1][r] = v.y;
    As[kk + 2][r] = v.z; As[kk + 3][r] = v.w;
  }

  const int tn = tid & 31;   // col group: cols tn*4..tn*4+3
  const int tm = tid >> 5;   // row group: rows tm*8..tm*8+7
  float acc[8][4];
  #pragma unroll
  for (int r = 0; r < 8; ++r)
    #pragma unroll
    for (int c = 0; c < 4; ++c) acc[r][c] = 0.f;

  const float4* W4 = (const float4*)W;
  for (int kc = 0; kc < 4; ++kc) {
    __syncthreads();
    #pragma unroll
    for (int i = 0; i < 4; ++i) {
      int j = tid + i * 256;      // 1024 f4 per 32x128 chunk
      ((float4*)Ws)[j] = W4[kc * 1024 + j];
    }
    __syncthreads();
    #pragma unroll 8
    for (int k = 0; k < 32; ++k) {
      const float* as = &As[kc * 32 + k][0];
      float4 a0 = *(const float4*)(as + tm * 8);
      float4 a1 = *(const float4*)(as + tm * 8 + 4);
      float4 wv = *(const float4*)(&Ws[k][tn * 4]);
      float av[8] = {a0.x, a0.y, a0.z, a0.w, a1.x, a1.y, a1.z, a1.w};
      float wr[4] = {wv.x, wv.y, wv.z, wv.w};
      #pragma unroll
      for (int r = 0; r < 8; ++r)
        #pragma unroll
        for (int c = 0; c < 4; ++c)
          acc[r][c] = fmaf(av[r], wr[c], acc[r][c]);
    }
  }

  float4 b4 = ((const float4*)bias)[tn];
  float bv[4] = {b4.x, b4.y, b4.z, b4.w};
  #pragma unroll
  for (int r = 0; r < 8; ++r) {
    int row = m0 + tm * 8 + r;
    if (row < M) {
      float o0 = acc[r][0] + bv[0];
      float o1 = acc[r][1] + bv[1];
      float o2 = acc[r][2] + bv[2];
      float o3 = acc[r][3] + bv[3];
      if (relu) {
        o0 = fmaxf(o0, 0.f); o1 = fmaxf(o1, 0.f);
        o2 = fmaxf(o2, 0.f); o3 = fmaxf(o3, 0.f);
      }
      float4 o = make_float4(o0, o1, o2, o3);
      *((float4*)&out[(size_t)row * CH + tn * 4]) = o;
    }
  }
}

extern "C" void kernel_launch(void* const* d_in, const int* in_sizes, int n_in,
                              void* d_out, int out_size, void* d_ws, size_t ws_size,
                              hipStream_t stream) {
  const float* x      = (const float*)d_in[0];
  const int*   ei     = (const int*)d_in[1];
  const float* W_base = (const float*)d_in[2];
  const float* b_base = (const float*)d_in[3];
  const float* W_mu   = (const float*)d_in[4];
  const float* b_mu   = (const float*)d_in[5];
  const float* W_ls   = (const float*)d_in[6];
  const float* b_ls   = (const float*)d_in[7];
  float* out = (float*)d_out;

  const int N = in_sizes[0] / CH;
  const int E = in_sizes[1] / 2;

  char* ws = (char*)d_ws;
  size_t off = 0;
  auto carve = [&](size_t bytes) -> void* {
    void* p = ws + off;
    off += (bytes + 511) & ~(size_t)511;
    return p;
  };
  int*   cnt    = (int*)carve((size_t)N * 4);
  int*   rowptr = (int*)carve((size_t)(N + 1) * 4);
  int*   cursor = (int*)carve((size_t)N * 4);
  int*   col    = (int*)carve((size_t)E * 4);
  float* dinv   = (float*)carve((size_t)N * 4);
  float* bufA   = (float*)carve((size_t)N * CH * 4);  // agg(x), then agg(h)
  float* bufH   = (float*)carve((size_t)N * CH * 4);  // h

  hipMemsetAsync(cnt, 0, (size_t)N * 4, stream);

  int eb = (E + 255) / 256;
  count_kernel<<<eb, 256, 0, stream>>>(ei, E, cnt);
  scan_kernel<<<1, 1024, 0, stream>>>(cnt, rowptr, cursor, dinv, N);
  fill_kernel<<<eb, 256, 0, stream>>>(ei, E, cursor, col);

  int ab = (N * 64 + 255) / 256;   // one wave per node
  int gb = (N + 63) / 64;

  agg_kernel<<<ab, 256, 0, stream>>>(x, rowptr, col, dinv, bufA, N);
  gemm_kernel<<<gb, 256, 0, stream>>>(bufA, W_base, b_base, bufH, N, 0);
  agg_kernel<<<ab, 256, 0, stream>>>(bufH, rowptr, col, dinv, bufA, N);
  gemm_kernel<<<gb, 256, 0, stream>>>(bufA, W_mu, b_mu, out, N, 1);
  gemm_kernel<<<gb, 256, 0, stream>>>(bufA, W_ls, b_ls, out + (size_t)N * CH, N, 1);
}

// Round 2
// 333.785 us; speedup vs baseline: 1.2443x; 1.2443x over previous
//
#include <hip/hip_runtime.h>

// GCN edge-predictor encoder:
//   deg/dinv -> CSR build -> aggA = A_norm @ x -> h = aggA@W_base + b
//   -> aggH = A_norm @ h -> m = relu(aggH@W_mu+b_mu), s = relu(aggH@W_ls+b_ls)
// Aggregation commutes with the linear layer, so layers 2a/2b share one
// aggregation pass (2 passes total instead of 3).
// R2: replaced the 91us single-block scan with a 3-phase device-wide scan.

#define CH 128
#define SCAN_CHUNK 1024   // elements per block in the scan phases

__global__ void count_kernel(const int* __restrict__ ei, int E, int* __restrict__ cnt) {
  int e = blockIdx.x * blockDim.x + threadIdx.x;
  if (e < E) atomicAdd(&cnt[ei[E + e]], 1);
}

// Phase 1: per-block sum of a 1024-element chunk of cnt.
__global__ __launch_bounds__(256) void scan_sum_kernel(const int* __restrict__ cnt,
    int n, int* __restrict__ bsum) {
  __shared__ int sdata[256];
  int base = blockIdx.x * SCAN_CHUNK;
  int tid = threadIdx.x;
  int s = 0;
  #pragma unroll
  for (int j = 0; j < 4; ++j) {
    int i = base + tid * 4 + j;
    if (i < n) s += cnt[i];
  }
  sdata[tid] = s;
  __syncthreads();
  for (int off = 128; off > 0; off >>= 1) {
    if (tid < off) sdata[tid] += sdata[tid + off];
    __syncthreads();
  }
  if (tid == 0) bsum[blockIdx.x] = sdata[0];
}

// Phase 2: one block exclusive-scans the block sums (nb <= 1024), writes total.
__global__ __launch_bounds__(256) void scan_bsum_kernel(int* __restrict__ bsum,
    int nb, int* __restrict__ total_out) {
  __shared__ int sdata[1024];
  int tid = threadIdx.x;
  #pragma unroll
  for (int j = 0; j < 4; ++j) {
    int i = tid * 4 + j;
    sdata[i] = (i < nb) ? bsum[i] : 0;
  }
  __syncthreads();
  if (tid == 0) {   // nb is tiny (~49); serial scan in one thread is fine
    int run = 0;
    for (int i = 0; i < nb; ++i) { int v = sdata[i]; sdata[i] = run; run += v; }
    *total_out = run;
  }
  __syncthreads();
  #pragma unroll
  for (int j = 0; j < 4; ++j) {
    int i = tid * 4 + j;
    if (i < nb) bsum[i] = sdata[i];
  }
}

// Phase 3: per-block local exclusive scan + block offset; write rowptr,
// cursor, dinv (rsqrt(deg+1)); last block writes rowptr[n] = total.
__global__ __launch_bounds__(256) void scan_fin_kernel(const int* __restrict__ cnt,
    int n, const int* __restrict__ bsum, const int* __restrict__ total,
    int* __restrict__ rowptr, int* __restrict__ cursor, float* __restrict__ dinv) {
  __shared__ int sthr[256];
  int base = blockIdx.x * SCAN_CHUNK;
  int tid = threadIdx.x;
  int v[4];
  int ts = 0;
  #pragma unroll
  for (int j = 0; j < 4; ++j) {
    int i = base + tid * 4 + j;
    v[j] = (i < n) ? cnt[i] : 0;
    ts += v[j];
  }
  sthr[tid] = ts;
  __syncthreads();
  // Hillis-Steele inclusive scan over 256 thread-sums (8 steps)
  for (int off = 1; off < 256; off <<= 1) {
    int t = (tid >= off) ? sthr[tid - off] : 0;
    __syncthreads();
    sthr[tid] += t;
    __syncthreads();
  }
  int excl = sthr[tid] - ts + bsum[blockIdx.x];
  #pragma unroll
  for (int j = 0; j < 4; ++j) {
    int i = base + tid * 4 + j;
    if (i < n) {
      rowptr[i] = excl;
      cursor[i] = excl;
      dinv[i]   = rsqrtf((float)(v[j] + 1));
      excl += v[j];
    }
  }
  if (blockIdx.x == 0 && tid == 0) rowptr[n] = *total;
}

__global__ void fill_kernel(const int* __restrict__ ei, int E,
                            int* __restrict__ cursor, int* __restrict__ col) {
  int e = blockIdx.x * blockDim.x + threadIdx.x;
  if (e < E) {
    int d = ei[E + e];
    int pos = atomicAdd(&cursor[d], 1);
    col[pos] = ei[e];
  }
}

// One wave (64 lanes) per node; lane owns 2 channels (float2).
// out[i] = dinv[i]^2 * feat[i] + sum_{e:dst=i} dinv[i]*dinv[src] * feat[src]
__global__ __launch_bounds__(256) void agg_kernel(const float* __restrict__ feat,
    const int* __restrict__ rowptr, const int* __restrict__ col,
    const float* __restrict__ dinv, float* __restrict__ out, int n) {
  int w = (blockIdx.x * 256 + threadIdx.x) >> 6;
  if (w >= n) return;
  int lane = threadIdx.x & 63;
  float di = dinv[w];
  const float2* f2 = (const float2*)feat;
  float2 x = f2[(size_t)w * 64 + lane];
  float2 acc;
  acc.x = x.x * di * di;
  acc.y = x.y * di * di;
  int s = rowptr[w], e = rowptr[w + 1];
  for (int j = s; j < e; ++j) {
    int src = col[j];
    float wt = di * dinv[src];
    float2 v = f2[(size_t)src * 64 + lane];
    acc.x = fmaf(wt, v.x, acc.x);
    acc.y = fmaf(wt, v.y, acc.y);
  }
  ((float2*)out)[(size_t)w * 64 + lane] = acc;
}

// f32 VALU GEMM: out[M,128] = A[M,128] @ W[128,128] + bias (+ optional relu).
// 64-row tile per block, 8x4 register micro-tile per thread, A staged
// transposed in LDS, W staged in 32-k chunks (48KB LDS total -> 3 blocks/CU).
__global__ __launch_bounds__(256) void gemm_kernel(
    const float* __restrict__ A, const float* __restrict__ W,
    const float* __restrict__ bias, float* __restrict__ out, int M, int relu) {
  __shared__ float As[128][64];   // [k][m] 32KB
  __shared__ float Ws[32][128];   // [k][n] 16KB
  const int tid = threadIdx.x;
  const int m0 = blockIdx.x * 64;

  const float4* A4 = (const float4*)A;
  #pragma unroll
  for (int i = 0; i < 8; ++i) {
    int j = tid + i * 256;        // float4 index within 64x128 tile
    int r = j >> 5;               // row 0..63
    int c = j & 31;               // f4-col 0..31
    int row = m0 + r;
    float4 v = make_float4(0.f, 0.f, 0.f, 0.f);
    if (row < M) v = A4[(size_t)row * 32 + c];
    int kk = c << 2;
    As[kk + 0][r] = v.x; As[kk + 1][r] = v.y;
    As[kk + 2][r] = v.z; As[kk + 3][r] = v.w;
  }

  const int tn = tid & 31;   // col group: cols tn*4..tn*4+3
  const int tm = tid >> 5;   // row group: rows tm*8..tm*8+7
  float acc[8][4];
  #pragma unroll
  for (int r = 0; r < 8; ++r)
    #pragma unroll
    for (int c = 0; c < 4; ++c) acc[r][c] = 0.f;

  const float4* W4 = (const float4*)W;
  for (int kc = 0; kc < 4; ++kc) {
    __syncthreads();
    #pragma unroll
    for (int i = 0; i < 4; ++i) {
      int j = tid + i * 256;      // 1024 f4 per 32x128 chunk
      ((float4*)Ws)[j] = W4[kc * 1024 + j];
    }
    __syncthreads();
    #pragma unroll 8
    for (int k = 0; k < 32; ++k) {
      const float* as = &As[kc * 32 + k][0];
      float4 a0 = *(const float4*)(as + tm * 8);
      float4 a1 = *(const float4*)(as + tm * 8 + 4);
      float4 wv = *(const float4*)(&Ws[k][tn * 4]);
      float av[8] = {a0.x, a0.y, a0.z, a0.w, a1.x, a1.y, a1.z, a1.w};
      float wr[4] = {wv.x, wv.y, wv.z, wv.w};
      #pragma unroll
      for (int r = 0; r < 8; ++r)
        #pragma unroll
        for (int c = 0; c < 4; ++c)
          acc[r][c] = fmaf(av[r], wr[c], acc[r][c]);
    }
  }

  float4 b4 = ((const float4*)bias)[tn];
  float bv[4] = {b4.x, b4.y, b4.z, b4.w};
  #pragma unroll
  for (int r = 0; r < 8; ++r) {
    int row = m0 + tm * 8 + r;
    if (row < M) {
      float o0 = acc[r][0] + bv[0];
      float o1 = acc[r][1] + bv[1];
      float o2 = acc[r][2] + bv[2];
      float o3 = acc[r][3] + bv[3];
      if (relu) {
        o0 = fmaxf(o0, 0.f); o1 = fmaxf(o1, 0.f);
        o2 = fmaxf(o2, 0.f); o3 = fmaxf(o3, 0.f);
      }
      float4 o = make_float4(o0, o1, o2, o3);
      *((float4*)&out[(size_t)row * CH + tn * 4]) = o;
    }
  }
}

extern "C" void kernel_launch(void* const* d_in, const int* in_sizes, int n_in,
                              void* d_out, int out_size, void* d_ws, size_t ws_size,
                              hipStream_t stream) {
  const float* x      = (const float*)d_in[0];
  const int*   ei     = (const int*)d_in[1];
  const float* W_base = (const float*)d_in[2];
  const float* b_base = (const float*)d_in[3];
  const float* W_mu   = (const float*)d_in[4];
  const float* b_mu   = (const float*)d_in[5];
  const float* W_ls   = (const float*)d_in[6];
  const float* b_ls   = (const float*)d_in[7];
  float* out = (float*)d_out;

  const int N = in_sizes[0] / CH;
  const int E = in_sizes[1] / 2;

  char* ws = (char*)d_ws;
  size_t off = 0;
  auto carve = [&](size_t bytes) -> void* {
    void* p = ws + off;
    off += (bytes + 511) & ~(size_t)511;
    return p;
  };
  int*   cnt    = (int*)carve((size_t)N * 4);
  int*   rowptr = (int*)carve((size_t)(N + 1) * 4);
  int*   cursor = (int*)carve((size_t)N * 4);
  int*   col    = (int*)carve((size_t)E * 4);
  float* dinv   = (float*)carve((size_t)N * 4);
  int*   bsum   = (int*)carve((size_t)2048 * 4);
  int*   total  = (int*)carve((size_t)4);
  float* bufA   = (float*)carve((size_t)N * CH * 4);  // agg(x), then agg(h)
  float* bufH   = (float*)carve((size_t)N * CH * 4);  // h

  hipMemsetAsync(cnt, 0, (size_t)N * 4, stream);

  int eb = (E + 255) / 256;
  int nb = (N + SCAN_CHUNK - 1) / SCAN_CHUNK;
  count_kernel<<<eb, 256, 0, stream>>>(ei, E, cnt);
  scan_sum_kernel<<<nb, 256, 0, stream>>>(cnt, N, bsum);
  scan_bsum_kernel<<<1, 256, 0, stream>>>(bsum, nb, total);
  scan_fin_kernel<<<nb, 256, 0, stream>>>(cnt, N, bsum, total, rowptr, cursor, dinv);
  fill_kernel<<<eb, 256, 0, stream>>>(ei, E, cursor, col);

  int ab = (N * 64 + 255) / 256;   // one wave per node
  int gb = (N + 63) / 64;

  agg_kernel<<<ab, 256, 0, stream>>>(x, rowptr, col, dinv, bufA, N);
  gemm_kernel<<<gb, 256, 0, stream>>>(bufA, W_base, b_base, bufH, N, 0);
  agg_kernel<<<ab, 256, 0, stream>>>(bufH, rowptr, col, dinv, bufA, N);
  gemm_kernel<<<gb, 256, 0, stream>>>(bufA, W_mu, b_mu, out, N, 1);
  gemm_kernel<<<gb, 256, 0, stream>>>(bufA, W_ls, b_ls, out + (size_t)N * CH, N, 1);
}

// Round 3
// 289.502 us; speedup vs baseline: 1.4346x; 1.1530x over previous
//
#include <hip/hip_runtime.h>

// GCN edge-predictor encoder, R3.
//   deg/dinv -> CSR -> x'=dinv*x -> t1=sum-gather(x') ; h'=dinv*(t1@Wb+bb)
//   -> t2=sum-gather(h') -> m=relu(t2@Wmu+bmu), s=relu(t2@Wls+bls)
// dinv is folded into the features (pre-scaled), so the gather inner loop is
// pure float4 adds with one dependent load level. Gather: 2 edges/wave-iter
// (lane halves), unroll x2 -> 4 row-loads in flight. gemm2+3 fused (dual-W).

#define CH 128
#define SCAN_CHUNK 1024

__global__ void count_kernel(const int* __restrict__ ei, int E, int* __restrict__ cnt) {
  int e = blockIdx.x * blockDim.x + threadIdx.x;
  if (e < E) atomicAdd(&cnt[ei[E + e]], 1);
}

__global__ __launch_bounds__(256) void scan_sum_kernel(const int* __restrict__ cnt,
    int n, int* __restrict__ bsum) {
  __shared__ int sdata[256];
  int base = blockIdx.x * SCAN_CHUNK;
  int tid = threadIdx.x;
  int s = 0;
  #pragma unroll
  for (int j = 0; j < 4; ++j) {
    int i = base + tid * 4 + j;
    if (i < n) s += cnt[i];
  }
  sdata[tid] = s;
  __syncthreads();
  for (int off = 128; off > 0; off >>= 1) {
    if (tid < off) sdata[tid] += sdata[tid + off];
    __syncthreads();
  }
  if (tid == 0) bsum[blockIdx.x] = sdata[0];
}

__global__ __launch_bounds__(256) void scan_bsum_kernel(int* __restrict__ bsum,
    int nb, int* __restrict__ total_out) {
  __shared__ int sdata[1024];
  int tid = threadIdx.x;
  #pragma unroll
  for (int j = 0; j < 4; ++j) {
    int i = tid * 4 + j;
    sdata[i] = (i < nb) ? bsum[i] : 0;
  }
  __syncthreads();
  if (tid == 0) {
    int run = 0;
    for (int i = 0; i < nb; ++i) { int v = sdata[i]; sdata[i] = run; run += v; }
    *total_out = run;
  }
  __syncthreads();
  #pragma unroll
  for (int j = 0; j < 4; ++j) {
    int i = tid * 4 + j;
    if (i < nb) bsum[i] = sdata[i];
  }
}

__global__ __launch_bounds__(256) void scan_fin_kernel(const int* __restrict__ cnt,
    int n, const int* __restrict__ bsum, const int* __restrict__ total,
    int* __restrict__ rowptr, int* __restrict__ cursor, float* __restrict__ dinv) {
  __shared__ int sthr[256];
  int base = blockIdx.x * SCAN_CHUNK;
  int tid = threadIdx.x;
  int v[4];
  int ts = 0;
  #pragma unroll
  for (int j = 0; j < 4; ++j) {
    int i = base + tid * 4 + j;
    v[j] = (i < n) ? cnt[i] : 0;
    ts += v[j];
  }
  sthr[tid] = ts;
  __syncthreads();
  for (int off = 1; off < 256; off <<= 1) {
    int t = (tid >= off) ? sthr[tid - off] : 0;
    __syncthreads();
    sthr[tid] += t;
    __syncthreads();
  }
  int excl = sthr[tid] - ts + bsum[blockIdx.x];
  #pragma unroll
  for (int j = 0; j < 4; ++j) {
    int i = base + tid * 4 + j;
    if (i < n) {
      rowptr[i] = excl;
      cursor[i] = excl;
      dinv[i]   = rsqrtf((float)(v[j] + 1));
      excl += v[j];
    }
  }
  if (blockIdx.x == 0 && tid == 0) rowptr[n] = *total;
}

__global__ void fill_kernel(const int* __restrict__ ei, int E,
                            int* __restrict__ cursor, int* __restrict__ col) {
  int e = blockIdx.x * blockDim.x + threadIdx.x;
  if (e < E) {
    int d = ei[E + e];
    int pos = atomicAdd(&cursor[d], 1);
    col[pos] = ei[e];
  }
}

// xp[i] = dinv[i] * x[i], float4-vectorized.
__global__ __launch_bounds__(256) void prescale_kernel(const float* __restrict__ x,
    const float* __restrict__ dinv, float* __restrict__ xp, int n) {
  int t = blockIdx.x * 256 + threadIdx.x;   // float4 index
  if (t < n * (CH / 4)) {
    float d = dinv[t >> 5];
    float4 v = ((const float4*)x)[t];
    ((float4*)xp)[t] = make_float4(v.x * d, v.y * d, v.z * d, v.w * d);
  }
}

// One wave per node. feat is pre-scaled; out[i] = dinv[i]*(feat[i]+sum feat[src]).
// Lane halves (g=0/1) process alternate edges; float4 per lane (32 lanes/row).
__global__ __launch_bounds__(256) void agg_kernel(const float* __restrict__ feat,
    const int* __restrict__ rowptr, const int* __restrict__ col,
    const float* __restrict__ dinv, float* __restrict__ out, int n) {
  int w = (blockIdx.x * 256 + threadIdx.x) >> 6;
  if (w >= n) return;
  int lane = threadIdx.x & 63;
  int g  = lane >> 5;        // edge-parity group
  int cl = lane & 31;        // float4 channel index
  const float4* f4 = (const float4*)feat;
  float4 acc = make_float4(0.f, 0.f, 0.f, 0.f);
  if (g == 0) acc = f4[(size_t)w * 32 + cl];   // self-loop term
  int s = rowptr[w], e = rowptr[w + 1];
  int j = s;
  for (; j + 4 <= e; j += 4) {
    int c0 = col[j + g];
    int c1 = col[j + 2 + g];
    float4 v0 = f4[(size_t)c0 * 32 + cl];
    float4 v1 = f4[(size_t)c1 * 32 + cl];
    acc.x += v0.x + v1.x;
    acc.y += v0.y + v1.y;
    acc.z += v0.z + v1.z;
    acc.w += v0.w + v1.w;
  }
  for (; j < e; j += 2) {
    int jj = j + g;
    if (jj < e) {
      int c = col[jj];
      float4 v = f4[(size_t)c * 32 + cl];
      acc.x += v.x; acc.y += v.y; acc.z += v.z; acc.w += v.w;
    }
  }
  acc.x += __shfl_xor(acc.x, 32);
  acc.y += __shfl_xor(acc.y, 32);
  acc.z += __shfl_xor(acc.z, 32);
  acc.w += __shfl_xor(acc.w, 32);
  if (g == 0) {
    float di = dinv[w];
    ((float4*)out)[(size_t)w * 32 + cl] =
        make_float4(acc.x * di, acc.y * di, acc.z * di, acc.w * di);
  }
}

// h' = dinv[row] * (A@W + b). 64-row tile, 8x4 register micro-tile.
__global__ __launch_bounds__(256) void gemm_scale_kernel(
    const float* __restrict__ A, const float* __restrict__ W,
    const float* __restrict__ bias, const float* __restrict__ dinv,
    float* __restrict__ out, int M) {
  __shared__ float As[128][64];
  __shared__ float Ws[32][128];
  const int tid = threadIdx.x;
  const int m0 = blockIdx.x * 64;

  const float4* A4 = (const float4*)A;
  #pragma unroll
  for (int i = 0; i < 8; ++i) {
    int j = tid + i * 256;
    int r = j >> 5, c = j & 31;
    int row = m0 + r;
    float4 v = make_float4(0.f, 0.f, 0.f, 0.f);
    if (row < M) v = A4[(size_t)row * 32 + c];
    int kk = c << 2;
    As[kk + 0][r] = v.x; As[kk + 1][r] = v.y;
    As[kk + 2][r] = v.z; As[kk + 3][r] = v.w;
  }

  const int tn = tid & 31;
  const int tm = tid >> 5;
  float acc[8][4];
  #pragma unroll
  for (int r = 0; r < 8; ++r)
    #pragma unroll
    for (int c = 0; c < 4; ++c) acc[r][c] = 0.f;

  const float4* W4 = (const float4*)W;
  for (int kc = 0; kc < 4; ++kc) {
    __syncthreads();
    #pragma unroll
    for (int i = 0; i < 4; ++i) {
      int j = tid + i * 256;
      ((float4*)Ws)[j] = W4[kc * 1024 + j];
    }
    __syncthreads();
    #pragma unroll 8
    for (int k = 0; k < 32; ++k) {
      const float* as = &As[kc * 32 + k][0];
      float4 a0 = *(const float4*)(as + tm * 8);
      float4 a1 = *(const float4*)(as + tm * 8 + 4);
      float4 wv = *(const float4*)(&Ws[k][tn * 4]);
      float av[8] = {a0.x, a0.y, a0.z, a0.w, a1.x, a1.y, a1.z, a1.w};
      float wr[4] = {wv.x, wv.y, wv.z, wv.w};
      #pragma unroll
      for (int r = 0; r < 8; ++r)
        #pragma unroll
        for (int c = 0; c < 4; ++c)
          acc[r][c] = fmaf(av[r], wr[c], acc[r][c]);
    }
  }

  float4 b4 = ((const float4*)bias)[tn];
  float bv[4] = {b4.x, b4.y, b4.z, b4.w};
  #pragma unroll
  for (int r = 0; r < 8; ++r) {
    int row = m0 + tm * 8 + r;
    if (row < M) {
      float d = dinv[row];
      float4 o = make_float4((acc[r][0] + bv[0]) * d, (acc[r][1] + bv[1]) * d,
                             (acc[r][2] + bv[2]) * d, (acc[r][3] + bv[3]) * d);
      *((float4*)&out[(size_t)row * CH + tn * 4]) = o;
    }
  }
}

// m = relu(A@W1+b1) -> out1 ; s = relu(A@W2+b2) -> out2. A staged once.
__global__ __launch_bounds__(256) void gemm_dual_kernel(
    const float* __restrict__ A,
    const float* __restrict__ W1, const float* __restrict__ b1,
    const float* __restrict__ W2, const float* __restrict__ b2,
    float* __restrict__ out1, float* __restrict__ out2, int M) {
  __shared__ float As[128][64];
  __shared__ float Ws[32][128];
  const int tid = threadIdx.x;
  const int m0 = blockIdx.x * 64;

  const float4* A4 = (const float4*)A;
  #pragma unroll
  for (int i = 0; i < 8; ++i) {
    int j = tid + i * 256;
    int r = j >> 5, c = j & 31;
    int row = m0 + r;
    float4 v = make_float4(0.f, 0.f, 0.f, 0.f);
    if (row < M) v = A4[(size_t)row * 32 + c];
    int kk = c << 2;
    As[kk + 0][r] = v.x; As[kk + 1][r] = v.y;
    As[kk + 2][r] = v.z; As[kk + 3][r] = v.w;
  }

  const int tn = tid & 31;
  const int tm = tid >> 5;

  #pragma unroll
  for (int wi = 0; wi < 2; ++wi) {
    const float* W  = wi ? W2 : W1;
    const float* bb = wi ? b2 : b1;
    float* out      = wi ? out2 : out1;
    float acc[8][4];
    #pragma unroll
    for (int r = 0; r < 8; ++r)
      #pragma unroll
      for (int c = 0; c < 4; ++c) acc[r][c] = 0.f;

    const float4* W4 = (const float4*)W;
    for (int kc = 0; kc < 4; ++kc) {
      __syncthreads();
      #pragma unroll
      for (int i = 0; i < 4; ++i) {
        int j = tid + i * 256;
        ((float4*)Ws)[j] = W4[kc * 1024 + j];
      }
      __syncthreads();
      #pragma unroll 8
      for (int k = 0; k < 32; ++k) {
        const float* as = &As[kc * 32 + k][0];
        float4 a0 = *(const float4*)(as + tm * 8);
        float4 a1 = *(const float4*)(as + tm * 8 + 4);
        float4 wv = *(const float4*)(&Ws[k][tn * 4]);
        float av[8] = {a0.x, a0.y, a0.z, a0.w, a1.x, a1.y, a1.z, a1.w};
        float wr[4] = {wv.x, wv.y, wv.z, wv.w};
        #pragma unroll
        for (int r = 0; r < 8; ++r)
          #pragma unroll
          for (int c = 0; c < 4; ++c)
            acc[r][c] = fmaf(av[r], wr[c], acc[r][c]);
      }
    }

    float4 b4 = ((const float4*)bb)[tn];
    float bv[4] = {b4.x, b4.y, b4.z, b4.w};
    #pragma unroll
    for (int r = 0; r < 8; ++r) {
      int row = m0 + tm * 8 + r;
      if (row < M) {
        float4 o = make_float4(fmaxf(acc[r][0] + bv[0], 0.f),
                               fmaxf(acc[r][1] + bv[1], 0.f),
                               fmaxf(acc[r][2] + bv[2], 0.f),
                               fmaxf(acc[r][3] + bv[3], 0.f));
        *((float4*)&out[(size_t)row * CH + tn * 4]) = o;
      }
    }
  }
}

extern "C" void kernel_launch(void* const* d_in, const int* in_sizes, int n_in,
                              void* d_out, int out_size, void* d_ws, size_t ws_size,
                              hipStream_t stream) {
  const float* x      = (const float*)d_in[0];
  const int*   ei     = (const int*)d_in[1];
  const float* W_base = (const float*)d_in[2];
  const float* b_base = (const float*)d_in[3];
  const float* W_mu   = (const float*)d_in[4];
  const float* b_mu   = (const float*)d_in[5];
  const float* W_ls   = (const float*)d_in[6];
  const float* b_ls   = (const float*)d_in[7];
  float* out = (float*)d_out;

  const int N = in_sizes[0] / CH;
  const int E = in_sizes[1] / 2;

  char* ws = (char*)d_ws;
  size_t off = 0;
  auto carve = [&](size_t bytes) -> void* {
    void* p = ws + off;
    off += (bytes + 511) & ~(size_t)511;
    return p;
  };
  int*   cnt    = (int*)carve((size_t)N * 4);
  int*   rowptr = (int*)carve((size_t)(N + 1) * 4);
  int*   cursor = (int*)carve((size_t)N * 4);
  int*   col    = (int*)carve((size_t)E * 4);
  float* dinv   = (float*)carve((size_t)N * 4);
  int*   bsum   = (int*)carve((size_t)2048 * 4);
  int*   total  = (int*)carve((size_t)4);
  float* bufA   = (float*)carve((size_t)N * CH * 4);  // xp, then h'
  float* bufB   = (float*)carve((size_t)N * CH * 4);  // agg out (t1, then t2)

  hipMemsetAsync(cnt, 0, (size_t)N * 4, stream);

  int eb = (E + 255) / 256;
  int nb = (N + SCAN_CHUNK - 1) / SCAN_CHUNK;
  count_kernel<<<eb, 256, 0, stream>>>(ei, E, cnt);
  scan_sum_kernel<<<nb, 256, 0, stream>>>(cnt, N, bsum);
  scan_bsum_kernel<<<1, 256, 0, stream>>>(bsum, nb, total);
  scan_fin_kernel<<<nb, 256, 0, stream>>>(cnt, N, bsum, total, rowptr, cursor, dinv);
  fill_kernel<<<eb, 256, 0, stream>>>(ei, E, cursor, col);

  int pb = (N * (CH / 4) + 255) / 256;
  int ab = (N * 64 + 255) / 256;
  int gb = (N + 63) / 64;

  prescale_kernel<<<pb, 256, 0, stream>>>(x, dinv, bufA, N);                 // xp
  agg_kernel<<<ab, 256, 0, stream>>>(bufA, rowptr, col, dinv, bufB, N);      // t1
  gemm_scale_kernel<<<gb, 256, 0, stream>>>(bufB, W_base, b_base, dinv, bufA, N); // h'
  agg_kernel<<<ab, 256, 0, stream>>>(bufA, rowptr, col, dinv, bufB, N);      // t2
  gemm_dual_kernel<<<gb, 256, 0, stream>>>(bufB, W_mu, b_mu, W_ls, b_ls,
                                           out, out + (size_t)N * CH, N);
}